// Round 14
// baseline (197.045 us; speedup 1.0000x reference)
//
#include <hip/hip_runtime.h>
#include <hip/hip_bf16.h>

typedef short bf16x8 __attribute__((ext_vector_type(8)));
typedef float f32x16 __attribute__((ext_vector_type(16)));

static constexpr int M_DIM = 16384;
static constexpr int N_DIM = 4096;
static constexpr int K_DIM = 1024;

static constexpr int CVT_BLOCKS = (M_DIM * K_DIM / 8) / 256;   // 8192
static constexpr int WT_BLOCKS  = N_DIM;                       // 4096 (R7 proven)

__device__ __forceinline__ unsigned short f2bf(float f) {
  union { float f; unsigned u; } v; v.f = f;
  unsigned r = v.u + 0x7FFFu + ((v.u >> 16) & 1u);
  return (unsigned short)(r >> 16);
}

// R7-proven fused prep: cvt blocks vectorized; one block per w^T column.
__global__ __launch_bounds__(256) void prep_kernel(
    const float* __restrict__ x, const float* __restrict__ a,
    const float* __restrict__ b, const float* __restrict__ s,
    unsigned short* __restrict__ xb, unsigned short* __restrict__ wT) {
  __shared__ float as_eff[8][64];
  __shared__ float bl[8][16];
  const int tid = threadIdx.x;

  if (blockIdx.x < CVT_BLOCKS) {
    const int i = (blockIdx.x * 256 + tid) * 2;
    float4 v0 = reinterpret_cast<const float4*>(x)[i];
    float4 v1 = reinterpret_cast<const float4*>(x)[i + 1];
    ushort4 o0, o1;
    o0.x = f2bf(v0.x); o0.y = f2bf(v0.y); o0.z = f2bf(v0.z); o0.w = f2bf(v0.w);
    o1.x = f2bf(v1.x); o1.y = f2bf(v1.y); o1.z = f2bf(v1.z); o1.w = f2bf(v1.w);
    reinterpret_cast<ushort4*>(xb)[i] = o0;
    reinterpret_cast<ushort4*>(xb)[i + 1] = o1;
    return;
  }

  const int n = blockIdx.x - CVT_BLOCKS;
  const int j = n >> 5, l = n & 31;

#pragma unroll
  for (int t = tid; t < 512; t += 256) {
    const int r = t >> 6, i = t & 63;
    as_eff[r][i] = a[(r * 64 + i) * 128 + j] * s[i * 128 + j];
  }
  if (tid < 128) {
    const int r = tid >> 4, kk = tid & 15;
    bl[r][kk] = b[(r * 16 + kk) * 32 + l];
  }
  __syncthreads();

  const int i = tid >> 2;
  const int kk0 = (tid & 3) * 4;
  float o[4] = {0.f, 0.f, 0.f, 0.f};
#pragma unroll
  for (int r = 0; r < 8; ++r) {
    const float av = as_eff[r][i];
#pragma unroll
    for (int q = 0; q < 4; ++q)
      o[q] += av * bl[r][kk0 + q];
  }
  ushort4 w4;
  w4.x = f2bf(o[0]); w4.y = f2bf(o[1]); w4.z = f2bf(o[2]); w4.w = f2bf(o[3]);
  *reinterpret_cast<ushort4*>(&wT[(size_t)n * K_DIM + tid * 4]) = w4;
}

// ------- 256x256 GEMM on 32x32x16 MFMA (floor -17%, half the instructions) -------
// C(M,N) = A(M,K) * BT(N,K)^T + bias ; A,BT bf16, C f32.
// 512 threads = 8 waves (2M x 4N); wave out 128x64 = 4x2 frags of 32x32.
// LDS: Al[2]+Bl[2] = 128 KiB; staging + swizzle relation (chunk ^= row&7)
// byte-identical to R6-R13. 2 barriers/K-tile, R6-proven vmcnt ledger:
// publish queue [B(t+1):4][A(t+1):4][B(t+2):4] -> WAITV(4); t=14 -> 0.
// Fragment (32x32x16): lane l: row = l&31, k-half hi = l>>5 (8 bf16 = 16B at
// chunk ks*2+hi). Reads k-slice-major, 6/slice; counted lgkm 6/12/6/0 (4-bit
// field, all encodable). C/D: col=lane&31, row=(reg&3)+8*(reg>>2)+4*hi [m74/m101].

#define PH_BARRIER __builtin_amdgcn_s_barrier()
#define SCHED0     __builtin_amdgcn_sched_barrier(0)
#define WAITV(N)   do { asm volatile("s_waitcnt vmcnt(" #N ")" ::: "memory"); SCHED0; } while (0)
#define WAITL(N)   do { asm volatile("s_waitcnt lgkmcnt(" #N ")" ::: "memory"); SCHED0; } while (0)

__global__ __launch_bounds__(512, 2) void gemm_kernel(
    const unsigned short* __restrict__ A, const unsigned short* __restrict__ BT,
    const float* __restrict__ bias, float* __restrict__ C) {
  __shared__ __align__(16) unsigned short Al[2][16384];
  __shared__ __align__(16) unsigned short Bl[2][16384];

  const int tid  = threadIdx.x;
  const int lane = tid & 63;
  const int wave = tid >> 6;
  const int wm = wave >> 2;
  const int wn = wave & 3;
  const int wr = wm * 128;
  const int wc = wn * 64;
  const int r32 = lane & 31;          // fragment row
  const int hi  = lane >> 5;          // k-half
  const int x7  = r32 & 7;            // row&7 (wr, wc, frag offsets are mult of 32)

  int bid = blockIdx.x;               // 1024 blocks = 64 groups x 16
  int gid = bid >> 4, lid = bid & 15;
  gid = ((gid & 7) << 3) | (gid >> 3);          // bijective, 64 % 8 == 0
  const int bm = (gid >> 2) * 4 + (lid >> 2);
  const int bn = (gid & 3) * 4 + (lid & 3);
  const int brow = bm * 256, bcol = bn * 256;

  const unsigned short* Abase = A + (size_t)brow * K_DIM;
  const unsigned short* Bbase = BT + (size_t)bcol * K_DIM;

  const int srow = tid >> 3;
  const int scol = ((((tid & 7) << 4) ^ ((srow & 7) << 4)) >> 1);
  const int ldsu = __builtin_amdgcn_readfirstlane(wave * 512);   // shorts

#define STG(dst, base, q, k0) __builtin_amdgcn_global_load_lds( \
    (const __attribute__((address_space(1))) void*)((base) + (size_t)((q)*64 + srow) * K_DIM + (k0) + scol), \
    (__attribute__((address_space(3))) void*)((dst) + (q)*4096 + ldsu), 16, 0, 0)

#define STG4(dst, base, k0) do { STG(dst, base, 0, k0); STG(dst, base, 1, k0); \
                                 STG(dst, base, 2, k0); STG(dst, base, 3, k0); } while (0)

  // k-slice ks (0..3): 4 A-frags + 2 B-frags, one b128 each
#define LDKS(PA, PB, ks_) { \
    const int ch_ = ((((ks_)*2 + hi) ^ x7) << 4); \
    _Pragma("unroll") for (int mi = 0; mi < 4; ++mi) \
      aF[mi][ks_] = *(const bf16x8*)((const char*)(PA) + (wr + mi * 32 + r32) * 128 + ch_); \
    _Pragma("unroll") for (int ni = 0; ni < 2; ++ni) \
      bF[ni][ks_] = *(const bf16x8*)((const char*)(PB) + (wc + ni * 32 + r32) * 128 + ch_); \
  }

#define MFMA8(ks_) do { __builtin_amdgcn_s_setprio(1); \
    _Pragma("unroll") for (int mi = 0; mi < 4; ++mi) \
    _Pragma("unroll") for (int ni = 0; ni < 2; ++ni) \
      acc[mi][ni] = __builtin_amdgcn_mfma_f32_32x32x16_bf16( \
          aF[mi][ks_], bF[ni][ks_], acc[mi][ni], 0, 0, 0); \
    __builtin_amdgcn_s_setprio(0); } while (0)

  f32x16 acc[4][2] = {};
  bf16x8 aF[4][4], bF[2][4];

  // prologue: B0+A0 (buf0) + B1 (buf1); WAITV(4) leaves B1 in flight.
  STG4(Bl[0], Bbase, 0);
  STG4(Al[0], Abase, 0);
  STG4(Bl[1], Bbase, 64);
  WAITV(4);
  PH_BARRIER;

  // K-tile: reads k-slice-major; lgkm ledger (in-order DS): after ks0+ks1 (12)
  // WAITL(6) completes ks0; issue ks2+ks3; WAITL(12) completes ks1; WAITL(6)
  // ks2; WAITL(0) all -> barrier -> SB (B-restage WAR-safe) -> ks3 reg-only.
#define TILE(PA, PB, SA, SB, VM) \
  LDKS(PA, PB, 0); LDKS(PA, PB, 1); SCHED0; \
  SA; \
  WAITL(6); \
  MFMA8(0); \
  LDKS(PA, PB, 2); LDKS(PA, PB, 3); SCHED0; \
  WAITL(12); \
  MFMA8(1); \
  WAITL(6); \
  MFMA8(2); \
  WAITL(0); \
  PH_BARRIER; \
  SB; \
  MFMA8(3); \
  VM; \
  PH_BARRIER;

  int k = 0;
#pragma unroll 1
  for (int i = 0; i < 7; ++i) {
    TILE(Al[0], Bl[0], STG4(Al[1], Abase, k + 64), STG4(Bl[0], Bbase, k + 128), WAITV(4));
    TILE(Al[1], Bl[1], STG4(Al[0], Abase, k + 128), STG4(Bl[1], Bbase, k + 192), WAITV(4));
    k += 128;
  }
  TILE(Al[0], Bl[0], STG4(Al[1], Abase, k + 64), (void)0, WAITV(0));
  TILE(Al[1], Bl[1], (void)0, (void)0, WAITV(0));

  // ---- epilogue: per-wave LDS transpose (16x68 slab, proven fences) ----
  // acc[fm][ni][reg]: col = wc + ni*32 + r32, row = fm*32 + (reg&3)+8*(reg>>2)+4*hi.
  // Process 16-row halves: mfh selects q = reg>>2 in {2mfh, 2mfh+1}.
  __syncthreads();
  float* T = (float*)&Al[0][0];
  float* Tw = T + wave * (16 * 68);
  const int col4 = lane & 15;
  const int rsel = lane >> 4;
  float4 bv = *(const float4*)&bias[bcol + wc + col4 * 4];

#pragma unroll
  for (int fm = 0; fm < 4; ++fm) {
#pragma unroll
    for (int mfh = 0; mfh < 2; ++mfh) {
#pragma unroll
      for (int ni = 0; ni < 2; ++ni)
#pragma unroll
        for (int qq = 0; qq < 2; ++qq)
#pragma unroll
          for (int r = 0; r < 4; ++r)
            Tw[(qq * 8 + hi * 4 + r) * 68 + ni * 32 + r32] = acc[fm][ni][(2 * mfh + qq) * 4 + r];
      WAITL(0);                                 // fence write->read (R2/R3 root cause)
#pragma unroll
      for (int rr = 0; rr < 4; ++rr) {
        float4 v = *(float4*)&Tw[(rr * 4 + rsel) * 68 + col4 * 4];
        v.x += bv.x; v.y += bv.y; v.z += bv.z; v.w += bv.w;
        *(float4*)&C[(size_t)(brow + wr + fm * 32 + mfh * 16 + rr * 4 + rsel) * N_DIM + bcol + wc + col4 * 4] = v;
      }
      WAITL(0);                                 // reads done before next overwrite
    }
  }
}

extern "C" void kernel_launch(void* const* d_in, const int* in_sizes, int n_in,
                              void* d_out, int out_size, void* d_ws, size_t ws_size,
                              hipStream_t stream) {
  const float* x    = (const float*)d_in[0];
  const float* a    = (const float*)d_in[1];
  const float* b    = (const float*)d_in[2];
  const float* s    = (const float*)d_in[3];
  const float* bias = (const float*)d_in[4];
  float* out = (float*)d_out;

  unsigned short* xb = (unsigned short*)d_ws;
  unsigned short* wT = (unsigned short*)((char*)d_ws + (size_t)M_DIM * K_DIM * 2);

  prep_kernel<<<CVT_BLOCKS + WT_BLOCKS, 256, 0, stream>>>(x, a, b, s, xb, wT);
  gemm_kernel<<<(M_DIM / 256) * (N_DIM / 256), 512, 0, stream>>>(xb, wT, bias, out);
}

// Round 15
// 180.188 us; speedup vs baseline: 1.0936x; 1.0936x over previous
//
#include <hip/hip_runtime.h>
#include <hip/hip_bf16.h>

typedef short bf16x8 __attribute__((ext_vector_type(8)));
typedef float f32x4 __attribute__((ext_vector_type(4)));

static constexpr int M_DIM = 16384;
static constexpr int N_DIM = 4096;
static constexpr int K_DIM = 1024;

static constexpr int CVT_BLOCKS = (M_DIM * K_DIM / 8) / 256;   // 8192
static constexpr int WT_BLOCKS  = N_DIM;                       // 4096

__device__ __forceinline__ unsigned short f2bf(float f) {
  union { float f; unsigned u; } v; v.f = f;
  unsigned r = v.u + 0x7FFFu + ((v.u >> 16) & 1u);
  return (unsigned short)(r >> 16);
}

// prep1: gather-once transposes. Blocks 0..127: as_effT[j][t] = a[t*128+j]*s[(t&63)*128+j]
// (t = r*64+i, 512 threads). Block 128: bT[l][r*16+kk] = b[(r*16+kk)*32+l].
__global__ __launch_bounds__(512) void prep1_kernel(
    const float* __restrict__ a, const float* __restrict__ b,
    const float* __restrict__ s, float* __restrict__ as_effT,
    float* __restrict__ bT) {
  const int tid = threadIdx.x;
  if (blockIdx.x < 128) {
    const int j = blockIdx.x;
    as_effT[j * 512 + tid] = a[(size_t)tid * 128 + j] * s[(tid & 63) * 128 + j];
  } else {
#pragma unroll
    for (int t = tid; t < 4096; t += 512) {
      const int l = t >> 7, rk = t & 127;
      bT[t] = b[(size_t)rk * 32 + l];
    }
  }
}

// prep2: blocks [0,CVT): x f32->bf16 (8/thread). Blocks [CVT, +4096): one w^T
// column each; all reads now COALESCED from as_effT/bT (R14 postmortem: the old
// 2M scattered a/s loads were the prep cost).
__global__ __launch_bounds__(256) void prep2_kernel(
    const float* __restrict__ x, const float* __restrict__ as_effT,
    const float* __restrict__ bT, unsigned short* __restrict__ xb,
    unsigned short* __restrict__ wT) {
  __shared__ float as_eff[512];     // [r][i]
  __shared__ float bl[128];         // [r][kk]
  const int tid = threadIdx.x;

  if (blockIdx.x < CVT_BLOCKS) {
    const int i = (blockIdx.x * 256 + tid) * 2;
    float4 v0 = reinterpret_cast<const float4*>(x)[i];
    float4 v1 = reinterpret_cast<const float4*>(x)[i + 1];
    ushort4 o0, o1;
    o0.x = f2bf(v0.x); o0.y = f2bf(v0.y); o0.z = f2bf(v0.z); o0.w = f2bf(v0.w);
    o1.x = f2bf(v1.x); o1.y = f2bf(v1.y); o1.z = f2bf(v1.z); o1.w = f2bf(v1.w);
    reinterpret_cast<ushort4*>(xb)[i] = o0;
    reinterpret_cast<ushort4*>(xb)[i + 1] = o1;
    return;
  }

  const int n = blockIdx.x - CVT_BLOCKS;
  const int j = n >> 5, l = n & 31;

  as_eff[tid] = as_effT[j * 512 + tid];
  as_eff[tid + 256] = as_effT[j * 512 + 256 + tid];
  if (tid < 128) bl[tid] = bT[l * 128 + tid];
  __syncthreads();

  const int i = tid >> 2;
  const int kk0 = (tid & 3) * 4;
  float o[4] = {0.f, 0.f, 0.f, 0.f};
#pragma unroll
  for (int r = 0; r < 8; ++r) {
    const float av = as_eff[r * 64 + i];
#pragma unroll
    for (int q = 0; q < 4; ++q)
      o[q] += av * bl[r * 16 + kk0 + q];
  }
  ushort4 w4;
  w4.x = f2bf(o[0]); w4.y = f2bf(o[1]); w4.z = f2bf(o[2]); w4.w = f2bf(o[3]);
  *reinterpret_cast<ushort4*>(&wT[(size_t)n * K_DIM + tid * 4]) = w4;
}

// ---- R13-proven 256x256 GEMM (16x16x32, WAR-free frag regs) — byte-identical ----
#define PH_BARRIER __builtin_amdgcn_s_barrier()
#define SCHED0     __builtin_amdgcn_sched_barrier(0)
#define WAITV(N)   do { asm volatile("s_waitcnt vmcnt(" #N ")" ::: "memory"); SCHED0; } while (0)
#define WAITL(N)   do { asm volatile("s_waitcnt lgkmcnt(" #N ")" ::: "memory"); SCHED0; } while (0)

__device__ __forceinline__ void quad_mfma(f32x4 (&acc)[8][4], const bf16x8 (&aH)[4][2],
                                          const bf16x8 (&bH)[2][2], int mbase, int nbase) {
  __builtin_amdgcn_s_setprio(1);
#pragma unroll
  for (int ks = 0; ks < 2; ++ks)
#pragma unroll
    for (int mi = 0; mi < 4; ++mi)
#pragma unroll
      for (int ni = 0; ni < 2; ++ni)
        acc[mbase + mi][nbase + ni] = __builtin_amdgcn_mfma_f32_16x16x32_bf16(
            aH[mi][ks], bH[ni][ks], acc[mbase + mi][nbase + ni], 0, 0, 0);
  __builtin_amdgcn_s_setprio(0);
}

__global__ __launch_bounds__(512, 2) void gemm8_kernel(
    const unsigned short* __restrict__ A, const unsigned short* __restrict__ BT,
    const float* __restrict__ bias, float* __restrict__ C) {
  __shared__ __align__(16) unsigned short Al[2][16384];
  __shared__ __align__(16) unsigned short Bl[2][16384];

  const int tid  = threadIdx.x;
  const int lane = tid & 63;
  const int wave = tid >> 6;
  const int wm = wave >> 2;
  const int wn = wave & 3;
  const int wr = wm * 128;
  const int wc = wn * 64;
  const int frow = lane & 15;
  const int kg = lane >> 4;
  const int swz0 = (kg * 16) ^ ((lane & 7) << 4);
  const int swz1 = (64 + kg * 16) ^ ((lane & 7) << 4);

  int bid = blockIdx.x;
  int gid = bid >> 4, lid = bid & 15;
  gid = ((gid & 7) << 3) | (gid >> 3);
  const int bm = (gid >> 2) * 4 + (lid >> 2);
  const int bn = (gid & 3) * 4 + (lid & 3);
  const int brow = bm * 256, bcol = bn * 256;

  const unsigned short* Abase = A + (size_t)brow * K_DIM;
  const unsigned short* Bbase = BT + (size_t)bcol * K_DIM;

  const int srow = tid >> 3;
  const int scol = ((((tid & 7) << 4) ^ ((srow & 7) << 4)) >> 1);
  const int ldsu = __builtin_amdgcn_readfirstlane(wave * 512);

#define STG(dst, base, q, k0) __builtin_amdgcn_global_load_lds( \
    (const __attribute__((address_space(1))) void*)((base) + (size_t)((q)*64 + srow) * K_DIM + (k0) + scol), \
    (__attribute__((address_space(3))) void*)((dst) + (q)*4096 + ldsu), 16, 0, 0)

#define STG4(dst, base, k0) do { STG(dst, base, 0, k0); STG(dst, base, 1, k0); \
                                 STG(dst, base, 2, k0); STG(dst, base, 3, k0); } while (0)

#define LOAD_AH(P, h, dst) { _Pragma("unroll") for (int mi = 0; mi < 4; ++mi) { \
    const char* p_ = (const char*)(P) + (wr + frow + ((h)*4 + mi) * 16) * 128; \
    dst[mi][0] = *(const bf16x8*)(p_ + swz0); dst[mi][1] = *(const bf16x8*)(p_ + swz1); } }

#define LOAD_BH(P, h, dst) { _Pragma("unroll") for (int ni = 0; ni < 2; ++ni) { \
    const char* p_ = (const char*)(P) + (wc + frow + ((h)*2 + ni) * 16) * 128; \
    dst[ni][0] = *(const bf16x8*)(p_ + swz0); dst[ni][1] = *(const bf16x8*)(p_ + swz1); } }

  f32x4 acc[8][4] = {};
  bf16x8 aF0[4][2], aF1[4][2], b0[2][2], b1[2][2];

  STG4(Bl[0], Bbase, 0);
  STG4(Al[0], Abase, 0);
  STG4(Bl[1], Bbase, 64);
  WAITV(4);
  PH_BARRIER;

#define TILE(PA, PB, SA, SB, VM) \
  LOAD_AH(PA, 0, aF0); SCHED0; \
  LOAD_BH(PB, 0, b0);  SCHED0; \
  LOAD_BH(PB, 1, b1);  SCHED0; \
  LOAD_AH(PA, 1, aF1); SCHED0; \
  SA; \
  WAITL(12); \
  quad_mfma(acc, aF0, b0, 0, 0); \
  WAITL(8); \
  quad_mfma(acc, aF0, b1, 0, 2); \
  WAITL(0); \
  PH_BARRIER; \
  SB; \
  quad_mfma(acc, aF1, b0, 4, 0); \
  quad_mfma(acc, aF1, b1, 4, 2); \
  VM; \
  PH_BARRIER;

  int k = 0;
#pragma unroll 1
  for (int i = 0; i < 7; ++i) {
    TILE(Al[0], Bl[0], STG4(Al[1], Abase, k + 64), STG4(Bl[0], Bbase, k + 128), WAITV(4));
    TILE(Al[1], Bl[1], STG4(Al[0], Abase, k + 128), STG4(Bl[1], Bbase, k + 192), WAITV(4));
    k += 128;
  }
  TILE(Al[0], Bl[0], STG4(Al[1], Abase, k + 64), (void)0, WAITV(0));
  TILE(Al[1], Bl[1], (void)0, (void)0, WAITV(0));

  __syncthreads();
  float* T = (float*)&Al[0][0];
  float* Tw = T + wave * (16 * 68);
  const int col4 = lane & 15;
  const int rsel = lane >> 4;
  float4 bv = *(const float4*)&bias[bcol + wc + col4 * 4];

#pragma unroll
  for (int mi = 0; mi < 8; ++mi) {
#pragma unroll
    for (int ni = 0; ni < 4; ++ni)
#pragma unroll
      for (int r = 0; r < 4; ++r)
        Tw[(kg * 4 + r) * 68 + ni * 16 + frow] = acc[mi][ni][r];
    WAITL(0);
#pragma unroll
    for (int rr = 0; rr < 4; ++rr) {
      float4 v = *(float4*)&Tw[(rr * 4 + rsel) * 68 + col4 * 4];
      v.x += bv.x; v.y += bv.y; v.z += bv.z; v.w += bv.w;
      *(float4*)&C[(size_t)(brow + wr + mi * 16 + rr * 4 + rsel) * N_DIM + bcol + wc + col4 * 4] = v;
    }
    WAITL(0);
  }
}

extern "C" void kernel_launch(void* const* d_in, const int* in_sizes, int n_in,
                              void* d_out, int out_size, void* d_ws, size_t ws_size,
                              hipStream_t stream) {
  const float* x    = (const float*)d_in[0];
  const float* a    = (const float*)d_in[1];
  const float* b    = (const float*)d_in[2];
  const float* s    = (const float*)d_in[3];
  const float* bias = (const float*)d_in[4];
  float* out = (float*)d_out;

  unsigned short* xb = (unsigned short*)d_ws;                                        // 32 MB
  unsigned short* wT = (unsigned short*)((char*)d_ws + (size_t)M_DIM * K_DIM * 2);   // 8 MB
  float* as_effT = (float*)((char*)d_ws + (size_t)M_DIM * K_DIM * 2 + (size_t)N_DIM * K_DIM * 2);
  float* bT = as_effT + 128 * 512;                                                   // +16 KB

  prep1_kernel<<<129, 512, 0, stream>>>(a, b, s, as_effT, bT);
  prep2_kernel<<<CVT_BLOCKS + WT_BLOCKS, 256, 0, stream>>>(x, as_effT, bT, xb, wT);
  gemm8_kernel<<<(M_DIM / 256) * (N_DIM / 256), 512, 0, stream>>>(xb, wT, bias, out);
}

// Round 16
// 178.881 us; speedup vs baseline: 1.1015x; 1.0073x over previous
//
#include <hip/hip_runtime.h>
#include <hip/hip_bf16.h>

typedef short bf16x8 __attribute__((ext_vector_type(8)));
typedef float f32x4 __attribute__((ext_vector_type(4)));

static constexpr int M_DIM = 16384;
static constexpr int N_DIM = 4096;
static constexpr int K_DIM = 1024;

static constexpr int CVT_BLOCKS = (M_DIM * K_DIM / 4) / 1024;  // 4096 (16 f32/thread)
static constexpr int WT_BLOCKS  = N_DIM / 4;                   // 1024 (4 cols/block)

__device__ __forceinline__ unsigned short f2bf(float f) {
  union { float f; unsigned u; } v; v.f = f;
  unsigned r = v.u + 0x7FFFu + ((v.u >> 16) & 1u);
  return (unsigned short)(r >> 16);
}

// prep1: gather-once transposes (R15-proven).
__global__ __launch_bounds__(512) void prep1_kernel(
    const float* __restrict__ a, const float* __restrict__ b,
    const float* __restrict__ s, float* __restrict__ as_effT,
    float* __restrict__ bT) {
  const int tid = threadIdx.x;
  if (blockIdx.x < 128) {
    const int j = blockIdx.x;
    as_effT[j * 512 + tid] = a[(size_t)tid * 128 + j] * s[(tid & 63) * 128 + j];
  } else {
#pragma unroll
    for (int t = tid; t < 4096; t += 512) {
      const int l = t >> 7, rk = t & 127;
      bT[t] = b[(size_t)rk * 32 + l];
    }
  }
}

// prep2: blocks [0,4096): x f32->bf16, 16 elems/thread, lane-contiguous bursts.
// Blocks [4096, +1024): 4 w^T columns each (share j -> one as_eff stage).
__global__ __launch_bounds__(256) void prep2_kernel(
    const float* __restrict__ x, const float* __restrict__ as_effT,
    const float* __restrict__ bT, unsigned short* __restrict__ xb,
    unsigned short* __restrict__ wT) {
  const int tid = threadIdx.x;

  if (blockIdx.x < CVT_BLOCKS) {
    const int base = blockIdx.x * 1024;          // in float4 units
    const float4* xf = reinterpret_cast<const float4*>(x);
    ushort4* xo = reinterpret_cast<ushort4*>(xb);
#pragma unroll
    for (int q = 0; q < 4; ++q) {
      float4 v = xf[base + q * 256 + tid];
      ushort4 o;
      o.x = f2bf(v.x); o.y = f2bf(v.y); o.z = f2bf(v.z); o.w = f2bf(v.w);
      xo[base + q * 256 + tid] = o;
    }
    return;
  }

  __shared__ float as_eff[512];     // [r*64+i]
  __shared__ float blq[4][128];     // [ll][r*16+kk]
  const int nb = blockIdx.x - CVT_BLOCKS;        // 0..1023
  const int j  = nb >> 3;                        // n0 = nb*4; j = n0>>5
  const int l0 = (nb & 7) * 4;                   // n0 & 31

  as_eff[tid]       = as_effT[j * 512 + tid];
  as_eff[tid + 256] = as_effT[j * 512 + 256 + tid];
  blq[tid >> 7][tid & 127]       = bT[(l0 + (tid >> 7)) * 128 + (tid & 127)];
  blq[2 + (tid >> 7)][tid & 127] = bT[(l0 + 2 + (tid >> 7)) * 128 + (tid & 127)];
  __syncthreads();

  const int i = tid >> 2;
  const int kk0 = (tid & 3) * 4;
  float av[8];
#pragma unroll
  for (int r = 0; r < 8; ++r) av[r] = as_eff[r * 64 + i];

#pragma unroll
  for (int ll = 0; ll < 4; ++ll) {
    float o[4] = {0.f, 0.f, 0.f, 0.f};
#pragma unroll
    for (int r = 0; r < 8; ++r)
#pragma unroll
      for (int q = 0; q < 4; ++q)
        o[q] += av[r] * blq[ll][r * 16 + kk0 + q];
    ushort4 w4;
    w4.x = f2bf(o[0]); w4.y = f2bf(o[1]); w4.z = f2bf(o[2]); w4.w = f2bf(o[3]);
    *reinterpret_cast<ushort4*>(&wT[(size_t)(nb * 4 + ll) * K_DIM + tid * 4]) = w4;
  }
}

// ---- R13-proven 256x256 GEMM (16x16x32, WAR-free frag regs) — byte-identical ----
#define PH_BARRIER __builtin_amdgcn_s_barrier()
#define SCHED0     __builtin_amdgcn_sched_barrier(0)
#define WAITV(N)   do { asm volatile("s_waitcnt vmcnt(" #N ")" ::: "memory"); SCHED0; } while (0)
#define WAITL(N)   do { asm volatile("s_waitcnt lgkmcnt(" #N ")" ::: "memory"); SCHED0; } while (0)

__device__ __forceinline__ void quad_mfma(f32x4 (&acc)[8][4], const bf16x8 (&aH)[4][2],
                                          const bf16x8 (&bH)[2][2], int mbase, int nbase) {
  __builtin_amdgcn_s_setprio(1);
#pragma unroll
  for (int ks = 0; ks < 2; ++ks)
#pragma unroll
    for (int mi = 0; mi < 4; ++mi)
#pragma unroll
      for (int ni = 0; ni < 2; ++ni)
        acc[mbase + mi][nbase + ni] = __builtin_amdgcn_mfma_f32_16x16x32_bf16(
            aH[mi][ks], bH[ni][ks], acc[mbase + mi][nbase + ni], 0, 0, 0);
  __builtin_amdgcn_s_setprio(0);
}

__global__ __launch_bounds__(512, 2) void gemm8_kernel(
    const unsigned short* __restrict__ A, const unsigned short* __restrict__ BT,
    const float* __restrict__ bias, float* __restrict__ C) {
  __shared__ __align__(16) unsigned short Al[2][16384];
  __shared__ __align__(16) unsigned short Bl[2][16384];

  const int tid  = threadIdx.x;
  const int lane = tid & 63;
  const int wave = tid >> 6;
  const int wm = wave >> 2;
  const int wn = wave & 3;
  const int wr = wm * 128;
  const int wc = wn * 64;
  const int frow = lane & 15;
  const int kg = lane >> 4;
  const int swz0 = (kg * 16) ^ ((lane & 7) << 4);
  const int swz1 = (64 + kg * 16) ^ ((lane & 7) << 4);

  int bid = blockIdx.x;
  int gid = bid >> 4, lid = bid & 15;
  gid = ((gid & 7) << 3) | (gid >> 3);
  const int bm = (gid >> 2) * 4 + (lid >> 2);
  const int bn = (gid & 3) * 4 + (lid & 3);
  const int brow = bm * 256, bcol = bn * 256;

  const unsigned short* Abase = A + (size_t)brow * K_DIM;
  const unsigned short* Bbase = BT + (size_t)bcol * K_DIM;

  const int srow = tid >> 3;
  const int scol = ((((tid & 7) << 4) ^ ((srow & 7) << 4)) >> 1);
  const int ldsu = __builtin_amdgcn_readfirstlane(wave * 512);

#define STG(dst, base, q, k0) __builtin_amdgcn_global_load_lds( \
    (const __attribute__((address_space(1))) void*)((base) + (size_t)((q)*64 + srow) * K_DIM + (k0) + scol), \
    (__attribute__((address_space(3))) void*)((dst) + (q)*4096 + ldsu), 16, 0, 0)

#define STG4(dst, base, k0) do { STG(dst, base, 0, k0); STG(dst, base, 1, k0); \
                                 STG(dst, base, 2, k0); STG(dst, base, 3, k0); } while (0)

#define LOAD_AH(P, h, dst) { _Pragma("unroll") for (int mi = 0; mi < 4; ++mi) { \
    const char* p_ = (const char*)(P) + (wr + frow + ((h)*4 + mi) * 16) * 128; \
    dst[mi][0] = *(const bf16x8*)(p_ + swz0); dst[mi][1] = *(const bf16x8*)(p_ + swz1); } }

#define LOAD_BH(P, h, dst) { _Pragma("unroll") for (int ni = 0; ni < 2; ++ni) { \
    const char* p_ = (const char*)(P) + (wc + frow + ((h)*2 + ni) * 16) * 128; \
    dst[ni][0] = *(const bf16x8*)(p_ + swz0); dst[ni][1] = *(const bf16x8*)(p_ + swz1); } }

  f32x4 acc[8][4] = {};
  bf16x8 aF0[4][2], aF1[4][2], b0[2][2], b1[2][2];

  STG4(Bl[0], Bbase, 0);
  STG4(Al[0], Abase, 0);
  STG4(Bl[1], Bbase, 64);
  WAITV(4);
  PH_BARRIER;

#define TILE(PA, PB, SA, SB, VM) \
  LOAD_AH(PA, 0, aF0); SCHED0; \
  LOAD_BH(PB, 0, b0);  SCHED0; \
  LOAD_BH(PB, 1, b1);  SCHED0; \
  LOAD_AH(PA, 1, aF1); SCHED0; \
  SA; \
  WAITL(12); \
  quad_mfma(acc, aF0, b0, 0, 0); \
  WAITL(8); \
  quad_mfma(acc, aF0, b1, 0, 2); \
  WAITL(0); \
  PH_BARRIER; \
  SB; \
  quad_mfma(acc, aF1, b0, 4, 0); \
  quad_mfma(acc, aF1, b1, 4, 2); \
  VM; \
  PH_BARRIER;

  int k = 0;
#pragma unroll 1
  for (int i = 0; i < 7; ++i) {
    TILE(Al[0], Bl[0], STG4(Al[1], Abase, k + 64), STG4(Bl[0], Bbase, k + 128), WAITV(4));
    TILE(Al[1], Bl[1], STG4(Al[0], Abase, k + 128), STG4(Bl[1], Bbase, k + 192), WAITV(4));
    k += 128;
  }
  TILE(Al[0], Bl[0], STG4(Al[1], Abase, k + 64), (void)0, WAITV(0));
  TILE(Al[1], Bl[1], (void)0, (void)0, WAITV(0));

  __syncthreads();
  float* T = (float*)&Al[0][0];
  float* Tw = T + wave * (16 * 68);
  const int col4 = lane & 15;
  const int rsel = lane >> 4;
  float4 bv = *(const float4*)&bias[bcol + wc + col4 * 4];

#pragma unroll
  for (int mi = 0; mi < 8; ++mi) {
#pragma unroll
    for (int ni = 0; ni < 4; ++ni)
#pragma unroll
      for (int r = 0; r < 4; ++r)
        Tw[(kg * 4 + r) * 68 + ni * 16 + frow] = acc[mi][ni][r];
    WAITL(0);
#pragma unroll
    for (int rr = 0; rr < 4; ++rr) {
      float4 v = *(float4*)&Tw[(rr * 4 + rsel) * 68 + col4 * 4];
      v.x += bv.x; v.y += bv.y; v.z += bv.z; v.w += bv.w;
      *(float4*)&C[(size_t)(brow + wr + mi * 16 + rr * 4 + rsel) * N_DIM + bcol + wc + col4 * 4] = v;
    }
    WAITL(0);
  }
}

extern "C" void kernel_launch(void* const* d_in, const int* in_sizes, int n_in,
                              void* d_out, int out_size, void* d_ws, size_t ws_size,
                              hipStream_t stream) {
  const float* x    = (const float*)d_in[0];
  const float* a    = (const float*)d_in[1];
  const float* b    = (const float*)d_in[2];
  const float* s    = (const float*)d_in[3];
  const float* bias = (const float*)d_in[4];
  float* out = (float*)d_out;

  unsigned short* xb = (unsigned short*)d_ws;                                        // 32 MB
  unsigned short* wT = (unsigned short*)((char*)d_ws + (size_t)M_DIM * K_DIM * 2);   // 8 MB
  float* as_effT = (float*)((char*)d_ws + (size_t)M_DIM * K_DIM * 2 + (size_t)N_DIM * K_DIM * 2);
  float* bT = as_effT + 128 * 512;                                                   // +16 KB

  prep1_kernel<<<129, 512, 0, stream>>>(a, b, s, as_effT, bT);
  prep2_kernel<<<CVT_BLOCKS + WT_BLOCKS, 256, 0, stream>>>(x, as_effT, bT, xb, wT);
  gemm8_kernel<<<(M_DIM / 256) * (N_DIM / 256), 512, 0, stream>>>(xb, wT, bias, out);
}

// Round 17
// 178.069 us; speedup vs baseline: 1.1066x; 1.0046x over previous
//
#include <hip/hip_runtime.h>
#include <hip/hip_bf16.h>

typedef short bf16x8 __attribute__((ext_vector_type(8)));
typedef float f32x4 __attribute__((ext_vector_type(4)));

static constexpr int M_DIM = 16384;
static constexpr int N_DIM = 4096;
static constexpr int K_DIM = 1024;

static constexpr int WT_BLOCKS  = 128;                         // one per j, FIRST
static constexpr int CVT_BLOCKS = (M_DIM * K_DIM / 4) / 1024;  // 4096 (16 f32/thread)

__device__ __forceinline__ unsigned short f2bf(float f) {
  union { float f; unsigned u; } v; v.f = f;
  unsigned r = v.u + 0x7FFFu + ((v.u >> 16) & 1u);
  return (unsigned short)(r >> 16);
}

// Single fused prep. Blocks [0,128): build w^T for one j (32 columns) —
// scattered a*s gather once per j (64K total), b staged coalesced into padded
// LDS [l][rk] (pad 132 -> 16B-aligned float4 reads, bank-stride 4, conflict-free).
// Blocks [128, +4096): x f32->bf16, 16 elems/thread, lane-contiguous bursts.
// wt blocks first so they launch early and hide under the BW-bound cvt blocks.
__global__ __launch_bounds__(256) void prep_kernel(
    const float* __restrict__ x, const float* __restrict__ a,
    const float* __restrict__ b, const float* __restrict__ s,
    unsigned short* __restrict__ xb, unsigned short* __restrict__ wT) {
  const int tid = threadIdx.x;

  if (blockIdx.x >= WT_BLOCKS) {
    const int base = (blockIdx.x - WT_BLOCKS) * 1024;   // float4 units
    const float4* xf = reinterpret_cast<const float4*>(x);
    ushort4* xo = reinterpret_cast<ushort4*>(xb);
#pragma unroll
    for (int q = 0; q < 4; ++q) {
      float4 v = xf[base + q * 256 + tid];
      ushort4 o;
      o.x = f2bf(v.x); o.y = f2bf(v.y); o.z = f2bf(v.z); o.w = f2bf(v.w);
      xo[base + q * 256 + tid] = o;
    }
    return;
  }

  __shared__ float as_eff[512];       // [r*64+i]
  __shared__ float bsh[32 * 132];     // [l][rk], pad 132
  const int j = blockIdx.x;

#pragma unroll
  for (int t = tid; t < 512; t += 256)
    as_eff[t] = a[(size_t)t * 128 + j] * s[(t & 63) * 128 + j];
#pragma unroll
  for (int t = tid; t < 4096; t += 256)
    bsh[(t & 31) * 132 + (t >> 5)] = b[t];     // b[rk*32+l] -> [l][rk]
  __syncthreads();

  const int i = tid >> 2;
  const int kk0 = (tid & 3) * 4;
  float av[8];
#pragma unroll
  for (int r = 0; r < 8; ++r) av[r] = as_eff[r * 64 + i];

#pragma unroll 4
  for (int l = 0; l < 32; ++l) {
    float o[4] = {0.f, 0.f, 0.f, 0.f};
#pragma unroll
    for (int r = 0; r < 8; ++r) {
      float4 bv4 = *reinterpret_cast<const float4*>(&bsh[l * 132 + r * 16 + kk0]);
      o[0] += av[r] * bv4.x; o[1] += av[r] * bv4.y;
      o[2] += av[r] * bv4.z; o[3] += av[r] * bv4.w;
    }
    ushort4 w4;
    w4.x = f2bf(o[0]); w4.y = f2bf(o[1]); w4.z = f2bf(o[2]); w4.w = f2bf(o[3]);
    *reinterpret_cast<ushort4*>(&wT[(size_t)(j * 32 + l) * K_DIM + tid * 4]) = w4;
  }
}

// ---- R13-proven 256x256 GEMM (16x16x32, WAR-free frag regs) — byte-identical ----
#define PH_BARRIER __builtin_amdgcn_s_barrier()
#define SCHED0     __builtin_amdgcn_sched_barrier(0)
#define WAITV(N)   do { asm volatile("s_waitcnt vmcnt(" #N ")" ::: "memory"); SCHED0; } while (0)
#define WAITL(N)   do { asm volatile("s_waitcnt lgkmcnt(" #N ")" ::: "memory"); SCHED0; } while (0)

__device__ __forceinline__ void quad_mfma(f32x4 (&acc)[8][4], const bf16x8 (&aH)[4][2],
                                          const bf16x8 (&bH)[2][2], int mbase, int nbase) {
  __builtin_amdgcn_s_setprio(1);
#pragma unroll
  for (int ks = 0; ks < 2; ++ks)
#pragma unroll
    for (int mi = 0; mi < 4; ++mi)
#pragma unroll
      for (int ni = 0; ni < 2; ++ni)
        acc[mbase + mi][nbase + ni] = __builtin_amdgcn_mfma_f32_16x16x32_bf16(
            aH[mi][ks], bH[ni][ks], acc[mbase + mi][nbase + ni], 0, 0, 0);
  __builtin_amdgcn_s_setprio(0);
}

__global__ __launch_bounds__(512, 2) void gemm8_kernel(
    const unsigned short* __restrict__ A, const unsigned short* __restrict__ BT,
    const float* __restrict__ bias, float* __restrict__ C) {
  __shared__ __align__(16) unsigned short Al[2][16384];
  __shared__ __align__(16) unsigned short Bl[2][16384];

  const int tid  = threadIdx.x;
  const int lane = tid & 63;
  const int wave = tid >> 6;
  const int wm = wave >> 2;
  const int wn = wave & 3;
  const int wr = wm * 128;
  const int wc = wn * 64;
  const int frow = lane & 15;
  const int kg = lane >> 4;
  const int swz0 = (kg * 16) ^ ((lane & 7) << 4);
  const int swz1 = (64 + kg * 16) ^ ((lane & 7) << 4);

  int bid = blockIdx.x;
  int gid = bid >> 4, lid = bid & 15;
  gid = ((gid & 7) << 3) | (gid >> 3);
  const int bm = (gid >> 2) * 4 + (lid >> 2);
  const int bn = (gid & 3) * 4 + (lid & 3);
  const int brow = bm * 256, bcol = bn * 256;

  const unsigned short* Abase = A + (size_t)brow * K_DIM;
  const unsigned short* Bbase = BT + (size_t)bcol * K_DIM;

  const int srow = tid >> 3;
  const int scol = ((((tid & 7) << 4) ^ ((srow & 7) << 4)) >> 1);
  const int ldsu = __builtin_amdgcn_readfirstlane(wave * 512);

#define STG(dst, base, q, k0) __builtin_amdgcn_global_load_lds( \
    (const __attribute__((address_space(1))) void*)((base) + (size_t)((q)*64 + srow) * K_DIM + (k0) + scol), \
    (__attribute__((address_space(3))) void*)((dst) + (q)*4096 + ldsu), 16, 0, 0)

#define STG4(dst, base, k0) do { STG(dst, base, 0, k0); STG(dst, base, 1, k0); \
                                 STG(dst, base, 2, k0); STG(dst, base, 3, k0); } while (0)

#define LOAD_AH(P, h, dst) { _Pragma("unroll") for (int mi = 0; mi < 4; ++mi) { \
    const char* p_ = (const char*)(P) + (wr + frow + ((h)*4 + mi) * 16) * 128; \
    dst[mi][0] = *(const bf16x8*)(p_ + swz0); dst[mi][1] = *(const bf16x8*)(p_ + swz1); } }

#define LOAD_BH(P, h, dst) { _Pragma("unroll") for (int ni = 0; ni < 2; ++ni) { \
    const char* p_ = (const char*)(P) + (wc + frow + ((h)*2 + ni) * 16) * 128; \
    dst[ni][0] = *(const bf16x8*)(p_ + swz0); dst[ni][1] = *(const bf16x8*)(p_ + swz1); } }

  f32x4 acc[8][4] = {};
  bf16x8 aF0[4][2], aF1[4][2], b0[2][2], b1[2][2];

  STG4(Bl[0], Bbase, 0);
  STG4(Al[0], Abase, 0);
  STG4(Bl[1], Bbase, 64);
  WAITV(4);
  PH_BARRIER;

#define TILE(PA, PB, SA, SB, VM) \
  LOAD_AH(PA, 0, aF0); SCHED0; \
  LOAD_BH(PB, 0, b0);  SCHED0; \
  LOAD_BH(PB, 1, b1);  SCHED0; \
  LOAD_AH(PA, 1, aF1); SCHED0; \
  SA; \
  WAITL(12); \
  quad_mfma(acc, aF0, b0, 0, 0); \
  WAITL(8); \
  quad_mfma(acc, aF0, b1, 0, 2); \
  WAITL(0); \
  PH_BARRIER; \
  SB; \
  quad_mfma(acc, aF1, b0, 4, 0); \
  quad_mfma(acc, aF1, b1, 4, 2); \
  VM; \
  PH_BARRIER;

  int k = 0;
#pragma unroll 1
  for (int i = 0; i < 7; ++i) {
    TILE(Al[0], Bl[0], STG4(Al[1], Abase, k + 64), STG4(Bl[0], Bbase, k + 128), WAITV(4));
    TILE(Al[1], Bl[1], STG4(Al[0], Abase, k + 128), STG4(Bl[1], Bbase, k + 192), WAITV(4));
    k += 128;
  }
  TILE(Al[0], Bl[0], STG4(Al[1], Abase, k + 64), (void)0, WAITV(0));
  TILE(Al[1], Bl[1], (void)0, (void)0, WAITV(0));

  __syncthreads();
  float* T = (float*)&Al[0][0];
  float* Tw = T + wave * (16 * 68);
  const int col4 = lane & 15;
  const int rsel = lane >> 4;
  float4 bv = *(const float4*)&bias[bcol + wc + col4 * 4];

#pragma unroll
  for (int mi = 0; mi < 8; ++mi) {
#pragma unroll
    for (int ni = 0; ni < 4; ++ni)
#pragma unroll
      for (int r = 0; r < 4; ++r)
        Tw[(kg * 4 + r) * 68 + ni * 16 + frow] = acc[mi][ni][r];
    WAITL(0);
#pragma unroll
    for (int rr = 0; rr < 4; ++rr) {
      float4 v = *(float4*)&Tw[(rr * 4 + rsel) * 68 + col4 * 4];
      v.x += bv.x; v.y += bv.y; v.z += bv.z; v.w += bv.w;
      *(float4*)&C[(size_t)(brow + wr + mi * 16 + rr * 4 + rsel) * N_DIM + bcol + wc + col4 * 4] = v;
    }
    WAITL(0);
  }
}

extern "C" void kernel_launch(void* const* d_in, const int* in_sizes, int n_in,
                              void* d_out, int out_size, void* d_ws, size_t ws_size,
                              hipStream_t stream) {
  const float* x    = (const float*)d_in[0];
  const float* a    = (const float*)d_in[1];
  const float* b    = (const float*)d_in[2];
  const float* s    = (const float*)d_in[3];
  const float* bias = (const float*)d_in[4];
  float* out = (float*)d_out;

  unsigned short* xb = (unsigned short*)d_ws;                                        // 32 MB
  unsigned short* wT = (unsigned short*)((char*)d_ws + (size_t)M_DIM * K_DIM * 2);   // 8 MB

  prep_kernel<<<WT_BLOCKS + CVT_BLOCKS, 256, 0, stream>>>(x, a, b, s, xb, wT);
  gemm8_kernel<<<(M_DIM / 256) * (N_DIM / 256), 512, 0, stream>>>(xb, wT, bias, out);
}

// Round 19
// 160.922 us; speedup vs baseline: 1.2245x; 1.1066x over previous
//
#include <hip/hip_runtime.h>
#include <hip/hip_bf16.h>

typedef short bf16x8 __attribute__((ext_vector_type(8)));
typedef float f32x4 __attribute__((ext_vector_type(4)));

static constexpr int M_DIM = 16384;
static constexpr int N_DIM = 4096;
static constexpr int K_DIM = 1024;

static constexpr int WT_BLOCKS  = 128;                         // one per j, FIRST
static constexpr int CVT_BLOCKS = (M_DIM * K_DIM / 4) / 1024;  // 4096 (16 f32/thread)

__device__ __forceinline__ unsigned short f2bf(float f) {
  union { float f; unsigned u; } v; v.f = f;
  unsigned r = v.u + 0x7FFFu + ((v.u >> 16) & 1u);
  return (unsigned short)(r >> 16);
}

// R17-proven single fused prep (byte-identical).
__global__ __launch_bounds__(256) void prep_kernel(
    const float* __restrict__ x, const float* __restrict__ a,
    const float* __restrict__ b, const float* __restrict__ s,
    unsigned short* __restrict__ xb, unsigned short* __restrict__ wT) {
  const int tid = threadIdx.x;

  if (blockIdx.x >= WT_BLOCKS) {
    const int base = (blockIdx.x - WT_BLOCKS) * 1024;   // float4 units
    const float4* xf = reinterpret_cast<const float4*>(x);
    ushort4* xo = reinterpret_cast<ushort4*>(xb);
#pragma unroll
    for (int q = 0; q < 4; ++q) {
      float4 v = xf[base + q * 256 + tid];
      ushort4 o;
      o.x = f2bf(v.x); o.y = f2bf(v.y); o.z = f2bf(v.z); o.w = f2bf(v.w);
      xo[base + q * 256 + tid] = o;
    }
    return;
  }

  __shared__ float as_eff[512];       // [r*64+i]
  __shared__ float bsh[32 * 132];     // [l][rk], pad 132
  const int j = blockIdx.x;

#pragma unroll
  for (int t = tid; t < 512; t += 256)
    as_eff[t] = a[(size_t)t * 128 + j] * s[(t & 63) * 128 + j];
#pragma unroll
  for (int t = tid; t < 4096; t += 256)
    bsh[(t & 31) * 132 + (t >> 5)] = b[t];     // b[rk*32+l] -> [l][rk]
  __syncthreads();

  const int i = tid >> 2;
  const int kk0 = (tid & 3) * 4;
  float av[8];
#pragma unroll
  for (int r = 0; r < 8; ++r) av[r] = as_eff[r * 64 + i];

#pragma unroll 4
  for (int l = 0; l < 32; ++l) {
    float o[4] = {0.f, 0.f, 0.f, 0.f};
#pragma unroll
    for (int r = 0; r < 8; ++r) {
      float4 bv4 = *reinterpret_cast<const float4*>(&bsh[l * 132 + r * 16 + kk0]);
      o[0] += av[r] * bv4.x; o[1] += av[r] * bv4.y;
      o[2] += av[r] * bv4.z; o[3] += av[r] * bv4.w;
    }
    ushort4 w4;
    w4.x = f2bf(o[0]); w4.y = f2bf(o[1]); w4.z = f2bf(o[2]); w4.w = f2bf(o[3]);
    *reinterpret_cast<ushort4*>(&wT[(size_t)(j * 32 + l) * K_DIM + tid * 4]) = w4;
  }
}

// ---- R13-proven 256x256 GEMM; single change vs R17: NON-TEMPORAL C stores ----
// (ext_vector f32x4 for the builtin — HIP_vector_type float4 is rejected.)
// Rationale: FETCH_SIZE 148MB vs ~40MB true input = ~108MB HBM refetch caused
// by the 256MB C stream evicting A/B panels from L2 (A logically read 16x,
// B 4x). C is write-once -> nt stores bypass L2 allocation, keep panels hot.
#define PH_BARRIER __builtin_amdgcn_s_barrier()
#define SCHED0     __builtin_amdgcn_sched_barrier(0)
#define WAITV(N)   do { asm volatile("s_waitcnt vmcnt(" #N ")" ::: "memory"); SCHED0; } while (0)
#define WAITL(N)   do { asm volatile("s_waitcnt lgkmcnt(" #N ")" ::: "memory"); SCHED0; } while (0)

__device__ __forceinline__ void quad_mfma(f32x4 (&acc)[8][4], const bf16x8 (&aH)[4][2],
                                          const bf16x8 (&bH)[2][2], int mbase, int nbase) {
  __builtin_amdgcn_s_setprio(1);
#pragma unroll
  for (int ks = 0; ks < 2; ++ks)
#pragma unroll
    for (int mi = 0; mi < 4; ++mi)
#pragma unroll
      for (int ni = 0; ni < 2; ++ni)
        acc[mbase + mi][nbase + ni] = __builtin_amdgcn_mfma_f32_16x16x32_bf16(
            aH[mi][ks], bH[ni][ks], acc[mbase + mi][nbase + ni], 0, 0, 0);
  __builtin_amdgcn_s_setprio(0);
}

__global__ __launch_bounds__(512, 2) void gemm8_kernel(
    const unsigned short* __restrict__ A, const unsigned short* __restrict__ BT,
    const float* __restrict__ bias, float* __restrict__ C) {
  __shared__ __align__(16) unsigned short Al[2][16384];
  __shared__ __align__(16) unsigned short Bl[2][16384];

  const int tid  = threadIdx.x;
  const int lane = tid & 63;
  const int wave = tid >> 6;
  const int wm = wave >> 2;
  const int wn = wave & 3;
  const int wr = wm * 128;
  const int wc = wn * 64;
  const int frow = lane & 15;
  const int kg = lane >> 4;
  const int swz0 = (kg * 16) ^ ((lane & 7) << 4);
  const int swz1 = (64 + kg * 16) ^ ((lane & 7) << 4);

  int bid = blockIdx.x;
  int gid = bid >> 4, lid = bid & 15;
  gid = ((gid & 7) << 3) | (gid >> 3);
  const int bm = (gid >> 2) * 4 + (lid >> 2);
  const int bn = (gid & 3) * 4 + (lid & 3);
  const int brow = bm * 256, bcol = bn * 256;

  const unsigned short* Abase = A + (size_t)brow * K_DIM;
  const unsigned short* Bbase = BT + (size_t)bcol * K_DIM;

  const int srow = tid >> 3;
  const int scol = ((((tid & 7) << 4) ^ ((srow & 7) << 4)) >> 1);
  const int ldsu = __builtin_amdgcn_readfirstlane(wave * 512);

#define STG(dst, base, q, k0) __builtin_amdgcn_global_load_lds( \
    (const __attribute__((address_space(1))) void*)((base) + (size_t)((q)*64 + srow) * K_DIM + (k0) + scol), \
    (__attribute__((address_space(3))) void*)((dst) + (q)*4096 + ldsu), 16, 0, 0)

#define STG4(dst, base, k0) do { STG(dst, base, 0, k0); STG(dst, base, 1, k0); \
                                 STG(dst, base, 2, k0); STG(dst, base, 3, k0); } while (0)

#define LOAD_AH(P, h, dst) { _Pragma("unroll") for (int mi = 0; mi < 4; ++mi) { \
    const char* p_ = (const char*)(P) + (wr + frow + ((h)*4 + mi) * 16) * 128; \
    dst[mi][0] = *(const bf16x8*)(p_ + swz0); dst[mi][1] = *(const bf16x8*)(p_ + swz1); } }

#define LOAD_BH(P, h, dst) { _Pragma("unroll") for (int ni = 0; ni < 2; ++ni) { \
    const char* p_ = (const char*)(P) + (wc + frow + ((h)*2 + ni) * 16) * 128; \
    dst[ni][0] = *(const bf16x8*)(p_ + swz0); dst[ni][1] = *(const bf16x8*)(p_ + swz1); } }

  f32x4 acc[8][4] = {};
  bf16x8 aF0[4][2], aF1[4][2], b0[2][2], b1[2][2];

  STG4(Bl[0], Bbase, 0);
  STG4(Al[0], Abase, 0);
  STG4(Bl[1], Bbase, 64);
  WAITV(4);
  PH_BARRIER;

#define TILE(PA, PB, SA, SB, VM) \
  LOAD_AH(PA, 0, aF0); SCHED0; \
  LOAD_BH(PB, 0, b0);  SCHED0; \
  LOAD_BH(PB, 1, b1);  SCHED0; \
  LOAD_AH(PA, 1, aF1); SCHED0; \
  SA; \
  WAITL(12); \
  quad_mfma(acc, aF0, b0, 0, 0); \
  WAITL(8); \
  quad_mfma(acc, aF0, b1, 0, 2); \
  WAITL(0); \
  PH_BARRIER; \
  SB; \
  quad_mfma(acc, aF1, b0, 4, 0); \
  quad_mfma(acc, aF1, b1, 4, 2); \
  VM; \
  PH_BARRIER;

  int k = 0;
#pragma unroll 1
  for (int i = 0; i < 7; ++i) {
    TILE(Al[0], Bl[0], STG4(Al[1], Abase, k + 64), STG4(Bl[0], Bbase, k + 128), WAITV(4));
    TILE(Al[1], Bl[1], STG4(Al[0], Abase, k + 128), STG4(Bl[1], Bbase, k + 192), WAITV(4));
    k += 128;
  }
  TILE(Al[0], Bl[0], STG4(Al[1], Abase, k + 64), (void)0, WAITV(0));
  TILE(Al[1], Bl[1], (void)0, (void)0, WAITV(0));

  __syncthreads();
  float* T = (float*)&Al[0][0];
  float* Tw = T + wave * (16 * 68);
  const int col4 = lane & 15;
  const int rsel = lane >> 4;
  float4 bv = *(const float4*)&bias[bcol + wc + col4 * 4];

#pragma unroll
  for (int mi = 0; mi < 8; ++mi) {
#pragma unroll
    for (int ni = 0; ni < 4; ++ni)
#pragma unroll
      for (int r = 0; r < 4; ++r)
        Tw[(kg * 4 + r) * 68 + ni * 16 + frow] = acc[mi][ni][r];
    WAITL(0);
#pragma unroll
    for (int rr = 0; rr < 4; ++rr) {
      f32x4 v = *(f32x4*)&Tw[(rr * 4 + rsel) * 68 + col4 * 4];
      v[0] += bv.x; v[1] += bv.y; v[2] += bv.z; v[3] += bv.w;
      __builtin_nontemporal_store(v,
          (f32x4*)&C[(size_t)(brow + wr + mi * 16 + rr * 4 + rsel) * N_DIM + bcol + wc + col4 * 4]);
    }
    WAITL(0);
  }
}

extern "C" void kernel_launch(void* const* d_in, const int* in_sizes, int n_in,
                              void* d_out, int out_size, void* d_ws, size_t ws_size,
                              hipStream_t stream) {
  const float* x    = (const float*)d_in[0];
  const float* a    = (const float*)d_in[1];
  const float* b    = (const float*)d_in[2];
  const float* s    = (const float*)d_in[3];
  const float* bias = (const float*)d_in[4];
  float* out = (float*)d_out;

  unsigned short* xb = (unsigned short*)d_ws;                                        // 32 MB
  unsigned short* wT = (unsigned short*)((char*)d_ws + (size_t)M_DIM * K_DIM * 2);   // 8 MB

  prep_kernel<<<WT_BLOCKS + CVT_BLOCKS, 256, 0, stream>>>(x, a, b, s, xb, wT);
  gemm8_kernel<<<(M_DIM / 256) * (N_DIM / 256), 512, 0, stream>>>(xb, wT, bias, out);
}